// Round 8
// baseline (530.063 us; speedup 1.0000x reference)
//
#include <hip/hip_runtime.h>
#include <hip/hip_bf16.h>
#include <math.h>

#define D_MODEL 1024
#define NH 16
#define DK 64
#define SEQ 2048
#define BATCH 2
#define MTOT (BATCH * SEQ)
#define NC (SEQ / 64)   // key chunks of 64

typedef unsigned short u16;
typedef unsigned int u32;
typedef short bf16x8 __attribute__((ext_vector_type(8)));   // K=32 A/B frag (4 VGPR)
typedef short bf16x4 __attribute__((ext_vector_type(4)));   // K=16 A/B frag (2 VGPR)
typedef float f32x4 __attribute__((ext_vector_type(4)));    // C/D frag

static constexpr float SCALE_LOG2 = 0.18033688011112042f;   // 0.125 * log2(e), folded into Q
static constexpr float MOFF = -32.0f;                       // fixed log2-domain offset
static constexpr float MASKADD = -1.0e5f;                   // masked keys -> exp2 == 0

__device__ __forceinline__ float fast_exp2(float x) {
#if __has_builtin(__builtin_amdgcn_exp2f)
    return __builtin_amdgcn_exp2f(x);   // native v_exp_f32
#else
    return __expf(x * 0.69314718056f);
#endif
}

__device__ __forceinline__ u32 pk2(float a, float b) {
    __hip_bfloat162 t = __float22bfloat162_rn(float2{a, b});
    return *(u32*)&t;
}
__device__ __forceinline__ ushort4 pk4u(float a, float b, float c, float d) {
    union { ushort4 s4; u32 w[2]; } u;
    u.w[0] = pk2(a, b); u.w[1] = pk2(c, d);
    return u.s4;
}

__device__ __forceinline__ f32x4 mfma32(bf16x8 a, bf16x8 b, f32x4 c) {
    return __builtin_amdgcn_mfma_f32_16x16x32_bf16(a, b, c, 0, 0, 0);
}

__device__ __forceinline__ void stage16(const u16* g, u16* lds_per_lane) {
#if __has_builtin(__builtin_amdgcn_global_load_lds)
    __builtin_amdgcn_global_load_lds((const __attribute__((address_space(1))) u32*)g,
                                     (__attribute__((address_space(3))) u32*)lds_per_lane,
                                     16, 0, 0);
#else
    *(uint4*)lds_per_lane = *(const uint4*)g;
#endif
}

// ------------- fp32 -> bf16 conversion of X, Wq|Wk|Wv + mask addend --------
__global__ __launch_bounds__(256) void convert_bf16(
    const float* __restrict__ X, const float* __restrict__ Wq,
    const float* __restrict__ Wk, const float* __restrict__ Wv,
    const int* __restrict__ mask,
    u16* __restrict__ Xb, u16* __restrict__ Wb, float* __restrict__ madsg)
{
    const int NX = MTOT * D_MODEL / 4;
    const int NW = D_MODEL * D_MODEL / 4;
    const int NM = MTOT / 4;
    int i = blockIdx.x * 256 + threadIdx.x;
    if (i >= NX + 3 * NW + NM) return;
    if (i >= NX + 3 * NW) {   // mask -> softmax C-init addend (log2 domain)
        int j = i - NX - 3 * NW;
        int4 m = ((const int4*)mask)[j];
        float4 o;
        o.x = m.x ? MASKADD : MOFF; o.y = m.y ? MASKADD : MOFF;
        o.z = m.z ? MASKADD : MOFF; o.w = m.w ? MASKADD : MOFF;
        ((float4*)madsg)[j] = o;
        return;
    }
    float4 v; u16* dst;
    if (i < NX)             { v = ((const float4*)X )[i];            dst = Xb + (size_t)i * 4; }
    else if (i < NX + NW)   { v = ((const float4*)Wq)[i - NX];       dst = Wb + (size_t)(i - NX) * 4; }
    else if (i < NX + 2*NW) { v = ((const float4*)Wk)[i - NX - NW];  dst = Wb + (size_t)NW * 4 + (size_t)(i - NX - NW) * 4; }
    else                    { v = ((const float4*)Wv)[i - NX - 2*NW];dst = Wb + (size_t)NW * 8 + (size_t)(i - NX - 2*NW) * 4; }
    *(ushort4*)dst = pk4u(v.x, v.y, v.z, v.w);
}

// ------------- QKV projection: MFMA GEMM (unchanged) ----------------------
__global__ __launch_bounds__(256, 2) void proj_mfma(
    const u16* __restrict__ Xb, const u16* __restrict__ Wb,
    const float* __restrict__ bq, const float* __restrict__ bk, const float* __restrict__ bv,
    u16* __restrict__ Qb, u16* __restrict__ Kb, u16* __restrict__ Vtb)
{
    __shared__ u16 As[128 * 32];
    __shared__ u16 Bs[128 * 32];

    const int which = blockIdx.z;
    const u16* __restrict__ W = Wb + (size_t)which * D_MODEL * D_MODEL;
    const float* __restrict__ bias = which == 0 ? bq : (which == 1 ? bk : bv);

    const int m0 = blockIdx.x * 128, n0 = blockIdx.y * 128;
    const int tid = threadIdx.x, lane = tid & 63, w = tid >> 6;
    const int quad = lane >> 4, l15 = lane & 15;
    const int wr = w >> 1, wc = w & 1;

    f32x4 acc[4][4];
#pragma unroll
    for (int i = 0; i < 4; i++)
#pragma unroll
        for (int j = 0; j < 4; j++) acc[i][j] = (f32x4)0.0f;

    const int srow = 32 * w + (lane >> 2);
    const int scol = (lane & 3) * 8;

    for (int k0 = 0; k0 < D_MODEL; k0 += 32) {
#pragma unroll
        for (int t = 0; t < 2; t++) {
            stage16(Xb + (size_t)(m0 + srow + 16 * t) * D_MODEL + k0 + scol,
                    &As[(32 * w + 16 * t) * 32 + lane * 8]);
            stage16(W + (size_t)(n0 + srow + 16 * t) * D_MODEL + k0 + scol,
                    &Bs[(32 * w + 16 * t) * 32 + lane * 8]);
        }
        __syncthreads();
        bf16x8 af[4], bfr[4];
#pragma unroll
        for (int i = 0; i < 4; i++)
            af[i] = *(const bf16x8*)&As[(wr * 64 + i * 16 + l15) * 32 + quad * 8];
#pragma unroll
        for (int j = 0; j < 4; j++)
            bfr[j] = *(const bf16x8*)&Bs[(wc * 64 + j * 16 + l15) * 32 + quad * 8];
        if (which < 2) {
#pragma unroll
            for (int i = 0; i < 4; i++)
#pragma unroll
                for (int j = 0; j < 4; j++)
                    acc[i][j] = __builtin_amdgcn_mfma_f32_16x16x32_bf16(bfr[j], af[i], acc[i][j], 0, 0, 0);
        } else {
#pragma unroll
            for (int i = 0; i < 4; i++)
#pragma unroll
                for (int j = 0; j < 4; j++)
                    acc[i][j] = __builtin_amdgcn_mfma_f32_16x16x32_bf16(af[i], bfr[j], acc[i][j], 0, 0, 0);
        }
        __syncthreads();
    }

    if (which < 2) {
        u16* __restrict__ Out = which == 0 ? Qb : Kb;
        const float scl = which == 0 ? SCALE_LOG2 : 1.0f;
        float4 bj4[4];
#pragma unroll
        for (int j = 0; j < 4; j++)
            bj4[j] = *(const float4*)&bias[n0 + wc * 64 + j * 16 + quad * 4];
#pragma unroll
        for (int i = 0; i < 4; i++) {
            int mcol = m0 + wr * 64 + i * 16 + l15;      // s index (C col)
            int b_ = mcol >> 11, s = mcol & (SEQ - 1);
#pragma unroll
            for (int j = 0; j < 4; j++) {
                int nrow = n0 + wc * 64 + j * 16 + quad * 4;  // d index (C row)
                int hh = nrow >> 6, d = nrow & 63;
                *(ushort4*)(Out + (((size_t)b_ * NH + hh) * SEQ + s) * DK + d) =
                    pk4u((acc[i][j][0] + bj4[j].x) * scl, (acc[i][j][1] + bj4[j].y) * scl,
                         (acc[i][j][2] + bj4[j].z) * scl, (acc[i][j][3] + bj4[j].w) * scl);
            }
        }
    } else {
        float bjv[4];
#pragma unroll
        for (int j = 0; j < 4; j++) bjv[j] = bias[n0 + wc * 64 + j * 16 + l15];
#pragma unroll
        for (int i = 0; i < 4; i++) {
            int srw = m0 + wr * 64 + i * 16 + quad * 4;  // s index (C row)
            int b_ = srw >> 11, s = srw & (SEQ - 1);
#pragma unroll
            for (int j = 0; j < 4; j++) {
                int ncol = n0 + wc * 64 + j * 16 + l15;  // d index (C col)
                int hh = ncol >> 6, d = ncol & 63;
                *(ushort4*)(Vtb + (((size_t)b_ * NH + hh) * DK + d) * SEQ + s) =
                    pk4u(acc[i][j][0] + bjv[j], acc[i][j][1] + bjv[j],
                         acc[i][j][2] + bjv[j], acc[i][j][3] + bjv[j]);
            }
        }
    }
}

// ------------- MFMA flash attention (pair-chunk PV @ K=32) ----------------
// Per chunk: S^T = K Q^T + addend (C-init carries mask & -32 offset),
// p = exp2 (native), pack to C-layout bf16. Per PAIR of chunks: PV and
// denominator via 16x16x32 MFMA using a virtual k-axis: element j of quad
// maps to even-chunk key quad*4+j (j<4) / odd-chunk key quad*4+j-4 (j>=4),
// so B = concat(pf_even, pf_odd), A = concat(vf_even, vf_odd) — register-
// only, no shuffles. K,V^T staged via global_load_lds into XOR-swizzled
// double buffers; same barriers/occupancy as round 7.
__global__ __launch_bounds__(256, 4) void attn_mfma(
    const u16* __restrict__ Qg, const u16* __restrict__ Kg, const u16* __restrict__ Vtg,
    const float* __restrict__ madsg, float* __restrict__ out)
{
    __shared__ u16 Ks[2][64 * 64];   // 8KB per buffer, swizzled [key][dk]
    __shared__ u16 Vs[2][64 * 64];   // 8KB per buffer, swizzled [dk][key]

    const int qt0 = blockIdx.x, h = blockIdx.y, b = blockIdx.z;
    const int tid = threadIdx.x, lane = tid & 63, w = tid >> 6;
    const int quad = lane >> 4, l15 = lane & 15;
    const size_t bh = (size_t)b * NH + h;
    const u16* __restrict__ Qp = Qg + (bh * SEQ + qt0 * 64 + w * 16) * DK;
    const u16* __restrict__ Kp = Kg + bh * SEQ * DK;
    const u16* __restrict__ Vp = Vtg + bh * DK * SEQ;
    const float* __restrict__ mp = madsg + b * SEQ;

    // persistent Q fragments (B operand): n=l15, k=quad*8+j
    bf16x8 qf[2];
#pragma unroll
    for (int half = 0; half < 2; half++)
        qf[half] = *(const bf16x8*)(Qp + (size_t)l15 * DK + half * 32 + quad * 8);

    // ones A-fragment (K=32) for the denominator MFMA
    bf16x8 ones8;
#pragma unroll
    for (int r = 0; r < 8; r++) ones8[r] = (short)0x3F80;  // bf16 1.0

    // staging maps (swizzle slot(row,c)=8*row+(c^(row&7)), 16B slots)
    const int srow_off = lane >> 3;
    const int sc = (lane & 7) ^ (lane >> 3);
    const int swzr = l15 & 7;
    const int kro0 = l15 * 64 + ((quad ^ swzr)) * 8;        // K frag half 0
    const int kro1 = l15 * 64 + (((4 + quad) ^ swzr)) * 8;  // K frag half 1
    const int vsub = (quad & 1) * 4;
    const int vq1 = quad >> 1;
    // V frag LDS offsets (u16 units) per ktl, invariant over chunks
    int vofs[4];
#pragma unroll
    for (int ktl = 0; ktl < 4; ktl++)
        vofs[ktl] = l15 * 64 + (((2 * ktl + vq1) ^ swzr)) * 8 + vsub;

    // stage chunk 0 into buffer 0
#pragma unroll
    for (int t = 0; t < 2; t++) {
        int row = (t * 4 + w) * 8 + srow_off;
        stage16(Kp + (size_t)row * DK + sc * 8, &Ks[0][((t * 4 + w) * 64 + lane) * 8]);
        stage16(Vp + (size_t)row * SEQ + sc * 8, &Vs[0][((t * 4 + w) * 64 + lane) * 8]);
    }
    __syncthreads();

    f32x4 O[4];
#pragma unroll
    for (int dt = 0; dt < 4; dt++) O[dt] = (f32x4)0.0f;
    f32x4 Lacc = (f32x4)0.0f;   // denominator accumulator (all rows identical)

    // pair-frags built across two chunks (half 0 = even chunk, half 1 = odd)
    union pk8 { bf16x8 v; u32 w[4]; };
    pk8 vf8[4][4];   // [dt][ktl]
    pk8 pf8[4];      // [ktl]

    for (int kt = 0; kt < NC; kt++) {
        const int bb = kt & 1;     // buffer AND pair-half
        // prefetch next chunk (async DMA into other buffer)
        if (kt + 1 < NC) {
#pragma unroll
            for (int t = 0; t < 2; t++) {
                int row = (t * 4 + w) * 8 + srow_off;
                stage16(Kp + (size_t)((kt + 1) * 64 + row) * DK + sc * 8,
                        &Ks[bb ^ 1][((t * 4 + w) * 64 + lane) * 8]);
                stage16(Vp + (size_t)row * SEQ + (kt + 1) * 64 + sc * 8,
                        &Vs[bb ^ 1][((t * 4 + w) * 64 + lane) * 8]);
            }
        }
        // mask/offset addends (global, broadcast, L1-hot) -> C-init
        f32x4 mav[4];
#pragma unroll
        for (int ktl = 0; ktl < 4; ktl++)
            mav[ktl] = *(const f32x4*)(mp + kt * 64 + ktl * 16 + quad * 4);
        // V frags from LDS into this pair-half
#pragma unroll
        for (int dt = 0; dt < 4; dt++)
#pragma unroll
            for (int ktl = 0; ktl < 4; ktl++) {
                uint2 t2 = *(const uint2*)&Vs[bb][dt * 1024 + vofs[ktl]];
                vf8[dt][ktl].w[bb * 2]     = t2.x;
                vf8[dt][ktl].w[bb * 2 + 1] = t2.y;
            }

        // S^T = K Q^T + addend: key = quad*4+r, q = l15 (score pre-scaled via Q)
        f32x4 St[4];
#pragma unroll
        for (int ktl = 0; ktl < 4; ktl++) {
            bf16x8 kf0 = *(const bf16x8*)&Ks[bb][ktl * 1024 + kro0];
            bf16x8 kf1 = *(const bf16x8*)&Ks[bb][ktl * 1024 + kro1];
            f32x4 acc = mav[ktl];
            acc = mfma32(kf0, qf[0], acc);
            acc = mfma32(kf1, qf[1], acc);
            St[ktl] = acc;
        }

        // p = exp2(S), pack into this pair-half (C-layout == virtual-k B-frag)
#pragma unroll
        for (int ktl = 0; ktl < 4; ktl++) {
            pf8[ktl].w[bb * 2]     = pk2(fast_exp2(St[ktl][0]), fast_exp2(St[ktl][1]));
            pf8[ktl].w[bb * 2 + 1] = pk2(fast_exp2(St[ktl][2]), fast_exp2(St[ktl][3]));
        }

        // pair complete on odd chunks: PV + denominator at K=32
        if (bb) {
#pragma unroll
            for (int ktl = 0; ktl < 4; ktl++) {
                Lacc = mfma32(ones8, pf8[ktl].v, Lacc);
#pragma unroll
                for (int dt = 0; dt < 4; dt++)
                    O[dt] = mfma32(vf8[dt][ktl].v, pf8[ktl].v, O[dt]);
            }
        }

        __syncthreads();  // drains prefetch DMA + guards buffer reuse
    }

    // epilogue: normalize, vectorized fp32 stores [B,S,D_MODEL]
    float inv = 1.0f / Lacc[0];
    int q = qt0 * 64 + w * 16 + l15;
    float* op = out + ((size_t)b * SEQ + q) * D_MODEL + h * DK;
#pragma unroll
    for (int dt = 0; dt < 4; dt++) {
        float4 o;
        o.x = O[dt][0] * inv; o.y = O[dt][1] * inv;
        o.z = O[dt][2] * inv; o.w = O[dt][3] * inv;
        *(float4*)(op + dt * 16 + quad * 4) = o;
    }
}

extern "C" void kernel_launch(void* const* d_in, const int* in_sizes, int n_in,
                              void* d_out, int out_size, void* d_ws, size_t ws_size,
                              hipStream_t stream)
{
    const float* X  = (const float*)d_in[0];
    const int* mask = (const int*)d_in[1];
    const float* Wq = (const float*)d_in[2];
    const float* bq = (const float*)d_in[3];
    const float* Wk = (const float*)d_in[4];
    const float* bk = (const float*)d_in[5];
    const float* Wv = (const float*)d_in[6];
    const float* bv = (const float*)d_in[7];
    float* out = (float*)d_out;

    u16* Xb  = (u16*)d_ws;
    u16* Wb  = Xb + (size_t)MTOT * D_MODEL;
    u16* Qb  = Wb + (size_t)3 * D_MODEL * D_MODEL;
    u16* Kb  = Qb + (size_t)BATCH * NH * SEQ * DK;
    u16* Vtb = Kb + (size_t)BATCH * NH * SEQ * DK;
    float* madsg = (float*)(Vtb + (size_t)BATCH * NH * SEQ * DK);

    const int ncvt = MTOT * D_MODEL / 4 + 3 * D_MODEL * D_MODEL / 4 + MTOT / 4;
    convert_bf16<<<(ncvt + 255) / 256, 256, 0, stream>>>(X, Wq, Wk, Wv, mask, Xb, Wb, madsg);
    proj_mfma<<<dim3(MTOT / 128, D_MODEL / 128, 3), 256, 0, stream>>>(Xb, Wb, bq, bk, bv, Qb, Kb, Vtb);
    attn_mfma<<<dim3(SEQ / 64, NH, BATCH), 256, 0, stream>>>(Qb, Kb, Vtb, madsg, out);
}